// Round 1
// baseline (184.976 us; speedup 1.0000x reference)
//
#include <hip/hip_runtime.h>

// GCN aggregation: out[t] = norm[t] * sum_{e:dst=t} norm[src]*x[src] + EPS*x[t]
// Round 10: (a) src-side of partition deleted -- out-degree via direct global
// atomicAdd(&deg[src],1) (fire-and-forget, L2-resident counters); (b) EPB
// 4096->2048 (grid 306->611 blocks) + register-stash of (s,t) between passes;
// (c) combo sort + gather fused into sortgather: src lists stay in LDS (no csr/
// row_start/row_cnt globals, csr hop of the dependent load chain now LDS);
// yh production split into a tiny BW-bound normyh kernel so yh is complete
// before any gather. 5 launches: init, partition, normyh, sortgather, cleanup.
constexpr int D        = 64;
constexpr float EPS    = 0.5f;
constexpr int BKT      = 128;
constexpr int CAPB_MAX = 2048;
constexpr int EPB      = 2048;   // edges per partition block
constexpr int NBMAX    = 1024;
constexpr int MAXOVF   = 65536;

__device__ __forceinline__ unsigned int f2bf(float f) {
    unsigned int u = __float_as_uint(f);
    return (u + 0x7FFFu + ((u >> 16) & 1u)) >> 16;   // RNE to bf16
}
__device__ __forceinline__ float bf2f_lo(unsigned int v) { return __uint_as_float(v << 16); }
__device__ __forceinline__ float bf2f_hi(unsigned int v) { return __uint_as_float(v & 0xFFFF0000u); }

// ---------------- main path ----------------

__global__ void init_kernel(int* __restrict__ deg, int* __restrict__ curD,
                            int* __restrict__ ovf_cnt, int n, int NB, int capb) {
    int i = blockIdx.x * blockDim.x + threadIdx.x;
    if (i < n)  deg[i]  = 0;
    if (i < NB) curD[i] = i * capb;
    if (i == 0) *ovf_cnt = 0;
}

__global__ __launch_bounds__(256)
void partition_kernel(const int* __restrict__ src, const int* __restrict__ dst,
                      int* __restrict__ curD, unsigned int* __restrict__ rec,
                      int* __restrict__ deg,
                      int* __restrict__ ovf_cnt, int* __restrict__ ovf,
                      int E, int NB, int capb) {
    __shared__ int histD[NBMAX];   // then reused as rank
    __shared__ int startD[NBMAX];
    const int base = blockIdx.x * EPB;
    const int tid  = threadIdx.x;
    for (int b = tid; b < NB; b += 256) histD[b] = 0;
    __syncthreads();

    int se[EPB / 256], te[EPB / 256];
    #pragma unroll
    for (int k = 0; k < EPB / 256; ++k) {
        int e = base + tid + k * 256;          // coalesced
        se[k] = -1;
        if (e < E) {
            int s = src[e], t = dst[e];
            se[k] = s; te[k] = t;
            atomicAdd(&histD[t >> 7], 1);
            atomicAdd(&deg[s], 1);             // fire-and-forget out-degree
        }
    }
    __syncthreads();
    for (int b = tid; b < NB; b += 256) {      // one global reserve atomic per (block,bucket)
        int c = histD[b];
        startD[b] = (c > 0) ? atomicAdd(&curD[b], c) : 0;
        histD[b] = 0;                          // reuse as rank
    }
    __syncthreads();
    #pragma unroll
    for (int k = 0; k < EPB / 256; ++k) {
        if (se[k] >= 0) {
            int s = se[k], t = te[k];
            int bD = t >> 7;
            int r  = atomicAdd(&histD[bD], 1);
            int pD = startD[bD] + r;
            if (pD < (bD + 1) * capb) {
                rec[pD] = ((unsigned int)s << 7) | (unsigned int)(t & (BKT - 1));
            } else {
                int i = atomicAdd(ovf_cnt, 1);
                if (i < MAXOVF) { ovf[2 * i] = s; ovf[2 * i + 1] = t; }
            }
        }
    }
}

// Tiny BW-bound pass: norm from deg, yh = bf16(norm*x). Must complete before
// any gather reads yh (separate launch).
__global__ __launch_bounds__(256)
void normyh_kernel(const int* __restrict__ deg, const float2* __restrict__ x2,
                   unsigned int* __restrict__ yh, int n) {
    const int b   = blockIdx.x;
    const int tid = threadIdx.x;
    __shared__ float nrm[BKT];
    if (tid < BKT) {
        int node = b * BKT + tid;
        float dv = (node < n) ? (float)deg[node] : 1.0f;
        nrm[tid] = rsqrtf(fmaxf(dv, 1.0f));
    }
    __syncthreads();
    int nodes = n - b * BKT;
    if (nodes > BKT) nodes = BKT;
    if (nodes < 0) nodes = 0;
    int total = nodes * (D / 2);               // float2 elements in this bucket
    size_t gbase = (size_t)b * BKT * (D / 2);
    for (int i = tid; i < total; i += 256) {   // contiguous -> coalesced
        float2 v = x2[gbase + i];
        float nm = nrm[i >> 5];
        yh[gbase + i] = f2bf(v.x * nm) | (f2bf(v.y * nm) << 16);
    }
}

// One block per bucket (512 threads = 8 waves). Phase 1: LDS counting sort of
// the bucket's dst-records -> per-node src lists in LDS. Phase 2: gather, 8
// nodes per wave (8 lanes x uint4 = 128B yh row), src indices read from LDS
// (short dependent chain), 8-deep unroll for memory-level parallelism.
__global__ __launch_bounds__(512)
void sortgather_kernel(const unsigned int* __restrict__ rec, const int* __restrict__ curD,
                       const int* __restrict__ deg, const uint4* __restrict__ yr4,
                       const float4* __restrict__ x4, float4* __restrict__ out4,
                       int n, int capb) {
    __shared__ unsigned int recs[CAPB_MAX];   // 8 KB
    __shared__ int srcs[CAPB_MAX];            // 8 KB
    __shared__ int hist[BKT];                 // per-node in-count (pristine after scan)
    __shared__ int scanv[BKT];
    __shared__ int rankb[BKT];
    __shared__ int rsL[BKT];                  // per-node exclusive start (pristine)
    const int b   = blockIdx.x;
    const int tid = threadIdx.x;

    int cnt = curD[b] - b * capb;
    if (cnt > capb) cnt = capb;
    for (int i = tid; i < cnt; i += 512) recs[i] = rec[(size_t)b * capb + i];
    if (tid < BKT) hist[tid] = 0;
    __syncthreads();
    for (int i = tid; i < cnt; i += 512) atomicAdd(&hist[recs[i] & (BKT - 1)], 1);
    __syncthreads();
    if (tid < BKT) scanv[tid] = hist[tid];
    __syncthreads();
    #pragma unroll
    for (int off = 1; off < BKT; off <<= 1) {          // Hillis-Steele inclusive scan
        int t = 0;
        if (tid < BKT && tid >= off) t = scanv[tid - off];
        __syncthreads();
        if (tid < BKT) scanv[tid] += t;
        __syncthreads();
    }
    if (tid < BKT) {
        int excl = scanv[tid] - hist[tid];
        rankb[tid] = excl;
        rsL[tid]   = excl;
    }
    __syncthreads();
    for (int i = tid; i < cnt; i += 512) {
        unsigned int v = recs[i];
        int pos = atomicAdd(&rankb[v & (BKT - 1)], 1);
        srcs[pos] = (int)(v >> 7);
    }
    __syncthreads();

    // ---- gather phase ----
    const int wave = tid >> 6;                 // 0..7
    const int lane = tid & 63;
    const int fl   = lane & 7;                 // uint4 index within 128B row
    const int oct  = lane >> 3;                // 0..7 -> node within group
    #pragma unroll
    for (int r = 0; r < 2; ++r) {
        int ln   = (r * 8 + wave) * 8 + oct;   // local node 0..127
        int node = b * BKT + ln;
        bool valid = node < n;
        int rsl = valid ? rsL[ln]  : 0;
        int cl  = valid ? hist[ln] : 0;
        int m = cl;                            // uniform loop count = wave-max
        m = max(m, __shfl_xor(m, 8));
        m = max(m, __shfl_xor(m, 16));
        m = max(m, __shfl_xor(m, 32));
        float a0 = 0.f, a1 = 0.f, a2 = 0.f, a3 = 0.f;
        float a4 = 0.f, a5 = 0.f, a6 = 0.f, a7 = 0.f;
        for (int k = 0; k < m; k += 8) {
            int sb[8];
            #pragma unroll
            for (int j = 0; j < 8; ++j) {      // 8 LDS reads issue together
                int kj = k + j;
                sb[j] = (kj < cl) ? srcs[rsl + kj] : -1;
            }
            #pragma unroll
            for (int j = 0; j < 8; ++j) {      // 8 row loads in flight
                bool take = sb[j] >= 0;
                int s = take ? sb[j] : 0;      // dummy hits node 0's cached row
                uint4 v = yr4[(size_t)s * 8 + fl];
                if (!take) { v.x = 0u; v.y = 0u; v.z = 0u; v.w = 0u; }
                a0 += bf2f_lo(v.x); a1 += bf2f_hi(v.x);
                a2 += bf2f_lo(v.y); a3 += bf2f_hi(v.y);
                a4 += bf2f_lo(v.z); a5 += bf2f_hi(v.z);
                a6 += bf2f_lo(v.w); a7 += bf2f_hi(v.w);
            }
        }
        if (valid) {
            float nt = rsqrtf(fmaxf((float)deg[node], 1.0f));
            size_t basei = (size_t)node * 16 + fl * 2;
            float4 xv0 = x4[basei], xv1 = x4[basei + 1];
            float4 r0, r1;
            r0.x = a0 * nt + EPS * xv0.x;  r0.y = a1 * nt + EPS * xv0.y;
            r0.z = a2 * nt + EPS * xv0.z;  r0.w = a3 * nt + EPS * xv0.w;
            r1.x = a4 * nt + EPS * xv1.x;  r1.y = a5 * nt + EPS * xv1.y;
            r1.z = a6 * nt + EPS * xv1.z;  r1.w = a7 * nt + EPS * xv1.w;
            out4[basei] = r0;              // coalesced: 32B/lane, 256B per oct
            out4[basei + 1] = r1;
        }
    }
}

// rare: dst-bucket overflow edges (expected 0)
__global__ void cleanup_kernel(const float* __restrict__ x, const int* __restrict__ deg,
                               const int* __restrict__ ovf_cnt, const int* __restrict__ ovf,
                               float* __restrict__ out) {
    int cnt = *ovf_cnt;
    if (cnt > MAXOVF) cnt = MAXOVF;
    long long total = (long long)cnt * D;
    long long stride = (long long)gridDim.x * blockDim.x;
    for (long long i = blockIdx.x * (long long)blockDim.x + threadIdx.x; i < total; i += stride) {
        int e = (int)(i >> 6), d = (int)(i & 63);
        int s = ovf[2 * e], t = ovf[2 * e + 1];
        float ns = rsqrtf(fmaxf((float)deg[s], 1.0f));
        float nt = rsqrtf(fmaxf((float)deg[t], 1.0f));
        atomicAdd(&out[(size_t)t * D + d], ns * nt * x[(size_t)s * D + d]);
    }
}

// ---------------- tiny-ws / big-n fallback (round-1 proven) ----------------

__global__ void fb_hist(const int* __restrict__ src, int* __restrict__ deg, int E) {
    int e = blockIdx.x * blockDim.x + threadIdx.x;
    if (e < E) atomicAdd(&deg[src[e]], 1);
}
__global__ void fb_norm(const int* __restrict__ deg, float* __restrict__ norm, int n) {
    int i = blockIdx.x * blockDim.x + threadIdx.x;
    if (i < n) norm[i] = rsqrtf(fmaxf((float)deg[i], 1.0f));
}
__global__ void fb_init_out(const float4* __restrict__ x, float4* __restrict__ out, int n4) {
    int i = blockIdx.x * blockDim.x + threadIdx.x;
    if (i < n4) {
        float4 v = x[i];
        out[i] = make_float4(v.x * EPS, v.y * EPS, v.z * EPS, v.w * EPS);
    }
}
__global__ void fb_scatter(const float* __restrict__ x, const int* __restrict__ src,
                           const int* __restrict__ dst, const float* __restrict__ norm,
                           float* __restrict__ out, int E) {
    long long tid = (long long)blockIdx.x * blockDim.x + threadIdx.x;
    int e = (int)(tid >> 6), d = (int)(tid & 63);
    if (e < E) {
        int s = src[e], t = dst[e];
        atomicAdd(&out[(size_t)t * D + d], norm[s] * norm[t] * x[(size_t)s * D + d]);
    }
}

// ---------------- launcher ----------------

extern "C" void kernel_launch(void* const* d_in, const int* in_sizes, int n_in,
                              void* d_out, int out_size, void* d_ws, size_t ws_size,
                              hipStream_t stream) {
    const float* x   = (const float*)d_in[0];
    const int*   src = (const int*)d_in[1];
    const int*   dst = (const int*)d_in[2];
    float* out = (float*)d_out;

    const int ND = in_sizes[0];
    const int E  = in_sizes[1];
    const int n  = ND / D;
    const int NB = (n + BKT - 1) / BKT;
    constexpr int B = 256;

    int capb = 0;
    for (int c : {2048, 1792}) {
        size_t need = (size_t)NB * c * 4                // rec (packed u32)
                    + (size_t)((n + 3) & ~3) * 4        // deg
                    + (size_t)ND * 2                    // yh
                    + (size_t)((NB + 63) & ~63) * 4     // curD
                    + (size_t)(64 + 2 * MAXOVF) * 4;    // ovf_cnt + ovf
        if (need <= ws_size) { capb = c; break; }
    }

    if (NB <= NBMAX && capb > 0 && n < (1 << 24)) {
        unsigned int* rec = (unsigned int*)d_ws;                         // NB*capb u32
        int* deg          = (int*)(rec + (size_t)NB * capb);             // n (16B-align kept)
        unsigned int* yh  = (unsigned int*)(deg + ((n + 3) & ~3));       // ND/2 u32
        int* curD         = (int*)(yh + ND / 2);                         // NB
        int* ovf_cnt      = curD + ((NB + 63) & ~63);                    // [0]
        int* ovf          = ovf_cnt + 64;                                // 2*MAXOVF

        int zmax  = (n > NB) ? n : NB;
        int zgrid = (zmax + B - 1) / B;
        init_kernel<<<zgrid, B, 0, stream>>>(deg, curD, ovf_cnt, n, NB, capb);
        partition_kernel<<<(E + EPB - 1) / EPB, B, 0, stream>>>(src, dst, curD, rec, deg,
                                                                ovf_cnt, ovf, E, NB, capb);
        normyh_kernel<<<NB, B, 0, stream>>>(deg, (const float2*)x, yh, n);
        sortgather_kernel<<<NB, 512, 0, stream>>>(rec, curD, deg, (const uint4*)yh,
                                                  (const float4*)x, (float4*)out, n, capb);
        cleanup_kernel<<<64, B, 0, stream>>>(x, deg, ovf_cnt, ovf, out);
    } else {
        int*   deg  = (int*)d_ws;
        float* norm = (float*)d_ws + n;
        hipMemsetAsync(deg, 0, (size_t)n * sizeof(int), stream);
        fb_hist<<<(E + B - 1) / B, B, 0, stream>>>(src, deg, E);
        fb_norm<<<(n + B - 1) / B, B, 0, stream>>>(deg, norm, n);
        fb_init_out<<<(ND / 4 + B - 1) / B, B, 0, stream>>>((const float4*)x, (float4*)out, ND / 4);
        long long total = (long long)E * D;
        fb_scatter<<<(int)((total + B - 1) / B), B, 0, stream>>>(x, src, dst, norm, out, E);
    }
}

// Round 2
// 181.082 us; speedup vs baseline: 1.0215x; 1.0215x over previous
//
#include <hip/hip_runtime.h>

// GCN aggregation: out[t] = norm[t] * sum_{e:dst=t} norm[src]*x[src] + EPS*x[t]
// Round 11: partition write-amplification fix. Round-10's regression was the
// rec[] scatter: per-(block,bucket) fragments of ~10B caused ~10x HBM write
// amplification (53 MB for 5 MB of rec). Fix: fragment = 4*EPB/NB bytes, so
// BKT 128->256 (NB 782->391) and EPB 2048->8192 (512-thr blocks, 16 edges/thr
// in registers) -> ~84B fragments, ~1.8x amp. curD is now a zero-based counter
// so deg+curD+ovf_cnt zero-init is ONE hipMemsetAsync (init launch deleted).
// 4 launches + 1 memset: partition, normyh, sortgather, cleanup.
constexpr int D        = 64;
constexpr float EPS    = 0.5f;
constexpr int BKT      = 256;    // nodes per bucket
constexpr int CAPB_MAX = 4096;
constexpr int EPB      = 8192;   // edges per partition block
constexpr int PTHREADS = 512;
constexpr int EPT      = EPB / PTHREADS;   // 16 edges per thread
constexpr int NBMAX    = 1024;
constexpr int MAXOVF   = 65536;

__device__ __forceinline__ unsigned int f2bf(float f) {
    unsigned int u = __float_as_uint(f);
    return (u + 0x7FFFu + ((u >> 16) & 1u)) >> 16;   // RNE to bf16
}
__device__ __forceinline__ float bf2f_lo(unsigned int v) { return __uint_as_float(v << 16); }
__device__ __forceinline__ float bf2f_hi(unsigned int v) { return __uint_as_float(v & 0xFFFF0000u); }

// ---------------- main path ----------------

__global__ __launch_bounds__(PTHREADS)
void partition_kernel(const int* __restrict__ src, const int* __restrict__ dst,
                      int* __restrict__ curD, unsigned int* __restrict__ rec,
                      int* __restrict__ deg,
                      int* __restrict__ ovf_cnt, int* __restrict__ ovf,
                      int E, int NB, int capb) {
    __shared__ int histD[NBMAX];   // then reused as rank
    __shared__ int startD[NBMAX];
    const int base = blockIdx.x * EPB;
    const int tid  = threadIdx.x;
    for (int b = tid; b < NB; b += PTHREADS) histD[b] = 0;
    __syncthreads();

    int se[EPT], te[EPT];
    #pragma unroll
    for (int k = 0; k < EPT; ++k) {
        int e = base + tid + k * PTHREADS;     // coalesced
        se[k] = -1;
        if (e < E) {
            int s = src[e], t = dst[e];
            se[k] = s; te[k] = t;
            atomicAdd(&histD[t >> 8], 1);
            atomicAdd(&deg[s], 1);             // fire-and-forget out-degree
        }
    }
    __syncthreads();
    for (int b = tid; b < NB; b += PTHREADS) { // one global reserve atomic per (block,bucket)
        int c = histD[b];
        startD[b] = (c > 0) ? atomicAdd(&curD[b], c) : 0;
        histD[b] = 0;                          // reuse as rank
    }
    __syncthreads();
    #pragma unroll
    for (int k = 0; k < EPT; ++k) {
        if (se[k] >= 0) {
            int s = se[k], t = te[k];
            int bD = t >> 8;
            int r  = atomicAdd(&histD[bD], 1);
            int p  = startD[bD] + r;           // zero-based within bucket
            if (p < capb) {
                rec[(size_t)bD * capb + p] = ((unsigned int)s << 8) | (unsigned int)(t & (BKT - 1));
            } else {
                int i = atomicAdd(ovf_cnt, 1);
                if (i < MAXOVF) { ovf[2 * i] = s; ovf[2 * i + 1] = t; }
            }
        }
    }
}

// Tiny BW-bound pass: norm from deg, yh = bf16(norm*x). Must complete before
// any gather reads yh (separate launch).
__global__ __launch_bounds__(256)
void normyh_kernel(const int* __restrict__ deg, const float2* __restrict__ x2,
                   unsigned int* __restrict__ yh, int n) {
    const int b   = blockIdx.x;
    const int tid = threadIdx.x;
    __shared__ float nrm[BKT];
    {
        int node = b * BKT + tid;
        float dv = (node < n) ? (float)deg[node] : 1.0f;
        nrm[tid] = rsqrtf(fmaxf(dv, 1.0f));
    }
    __syncthreads();
    int nodes = n - b * BKT;
    if (nodes > BKT) nodes = BKT;
    if (nodes < 0) nodes = 0;
    int total = nodes * (D / 2);               // float2 elements in this bucket
    size_t gbase = (size_t)b * BKT * (D / 2);
    for (int i = tid; i < total; i += 256) {   // contiguous -> coalesced
        float2 v = x2[gbase + i];
        float nm = nrm[i >> 5];
        yh[gbase + i] = f2bf(v.x * nm) | (f2bf(v.y * nm) << 16);
    }
}

// One block per bucket (512 threads = 8 waves). Phase 1: LDS counting sort of
// the bucket's dst-records -> per-node src lists in LDS. Phase 2: gather, 8
// nodes per wave (8 lanes x uint4 = 128B yh row), src indices read from LDS
// (short dependent chain), 8-deep unroll for memory-level parallelism.
__global__ __launch_bounds__(512)
void sortgather_kernel(const unsigned int* __restrict__ rec, const int* __restrict__ curD,
                       const int* __restrict__ deg, const uint4* __restrict__ yr4,
                       const float4* __restrict__ x4, float4* __restrict__ out4,
                       int n, int capb) {
    __shared__ unsigned int recs[CAPB_MAX];   // 16 KB
    __shared__ int srcs[CAPB_MAX];            // 16 KB
    __shared__ int hist[BKT];                 // per-node in-count (pristine after scan)
    __shared__ int scanv[BKT];
    __shared__ int rankb[BKT];
    __shared__ int rsL[BKT];                  // per-node exclusive start (pristine)
    __shared__ float nrmL[BKT];               // per-node dst norm
    const int b   = blockIdx.x;
    const int tid = threadIdx.x;

    int cnt = curD[b];
    if (cnt > capb) cnt = capb;
    for (int i = tid; i < cnt; i += 512) recs[i] = rec[(size_t)b * capb + i];
    if (tid < BKT) {
        hist[tid] = 0;
        int node = b * BKT + tid;
        float dv = (node < n) ? (float)deg[node] : 1.0f;
        nrmL[tid] = rsqrtf(fmaxf(dv, 1.0f));
    }
    __syncthreads();
    for (int i = tid; i < cnt; i += 512) atomicAdd(&hist[recs[i] & (BKT - 1)], 1);
    __syncthreads();
    if (tid < BKT) scanv[tid] = hist[tid];
    __syncthreads();
    #pragma unroll
    for (int off = 1; off < BKT; off <<= 1) {          // Hillis-Steele inclusive scan
        int t = 0;
        if (tid < BKT && tid >= off) t = scanv[tid - off];
        __syncthreads();
        if (tid < BKT) scanv[tid] += t;
        __syncthreads();
    }
    if (tid < BKT) {
        int excl = scanv[tid] - hist[tid];
        rankb[tid] = excl;
        rsL[tid]   = excl;
    }
    __syncthreads();
    for (int i = tid; i < cnt; i += 512) {
        unsigned int v = recs[i];
        int pos = atomicAdd(&rankb[v & (BKT - 1)], 1);
        srcs[pos] = (int)(v >> 8);
    }
    __syncthreads();

    // ---- gather phase ----
    const int wave = tid >> 6;                 // 0..7
    const int lane = tid & 63;
    const int fl   = lane & 7;                 // uint4 index within 128B row
    const int oct  = lane >> 3;                // 0..7 -> node within group
    #pragma unroll
    for (int r = 0; r < BKT / 64; ++r) {       // 4 rounds of 64 nodes
        int ln   = r * 64 + wave * 8 + oct;    // local node 0..255
        int node = b * BKT + ln;
        bool valid = node < n;
        int rsl = valid ? rsL[ln]  : 0;
        int cl  = valid ? hist[ln] : 0;
        int m = cl;                            // uniform loop count = wave-max
        m = max(m, __shfl_xor(m, 8));
        m = max(m, __shfl_xor(m, 16));
        m = max(m, __shfl_xor(m, 32));
        float a0 = 0.f, a1 = 0.f, a2 = 0.f, a3 = 0.f;
        float a4 = 0.f, a5 = 0.f, a6 = 0.f, a7 = 0.f;
        for (int k = 0; k < m; k += 8) {
            int sb[8];
            #pragma unroll
            for (int j = 0; j < 8; ++j) {      // 8 LDS reads issue together
                int kj = k + j;
                sb[j] = (kj < cl) ? srcs[rsl + kj] : -1;
            }
            #pragma unroll
            for (int j = 0; j < 8; ++j) {      // 8 row loads in flight
                bool take = sb[j] >= 0;
                int s = take ? sb[j] : 0;      // dummy hits node 0's cached row
                uint4 v = yr4[(size_t)s * 8 + fl];
                if (!take) { v.x = 0u; v.y = 0u; v.z = 0u; v.w = 0u; }
                a0 += bf2f_lo(v.x); a1 += bf2f_hi(v.x);
                a2 += bf2f_lo(v.y); a3 += bf2f_hi(v.y);
                a4 += bf2f_lo(v.z); a5 += bf2f_hi(v.z);
                a6 += bf2f_lo(v.w); a7 += bf2f_hi(v.w);
            }
        }
        if (valid) {
            float nt = nrmL[ln];
            size_t basei = (size_t)node * 16 + fl * 2;
            float4 xv0 = x4[basei], xv1 = x4[basei + 1];
            float4 r0, r1;
            r0.x = a0 * nt + EPS * xv0.x;  r0.y = a1 * nt + EPS * xv0.y;
            r0.z = a2 * nt + EPS * xv0.z;  r0.w = a3 * nt + EPS * xv0.w;
            r1.x = a4 * nt + EPS * xv1.x;  r1.y = a5 * nt + EPS * xv1.y;
            r1.z = a6 * nt + EPS * xv1.z;  r1.w = a7 * nt + EPS * xv1.w;
            out4[basei] = r0;              // coalesced: 32B/lane, 256B per oct
            out4[basei + 1] = r1;
        }
    }
}

// rare: dst-bucket overflow edges (expected 0)
__global__ void cleanup_kernel(const float* __restrict__ x, const int* __restrict__ deg,
                               const int* __restrict__ ovf_cnt, const int* __restrict__ ovf,
                               float* __restrict__ out) {
    int cnt = *ovf_cnt;
    if (cnt > MAXOVF) cnt = MAXOVF;
    long long total = (long long)cnt * D;
    long long stride = (long long)gridDim.x * blockDim.x;
    for (long long i = blockIdx.x * (long long)blockDim.x + threadIdx.x; i < total; i += stride) {
        int e = (int)(i >> 6), d = (int)(i & 63);
        int s = ovf[2 * e], t = ovf[2 * e + 1];
        float ns = rsqrtf(fmaxf((float)deg[s], 1.0f));
        float nt = rsqrtf(fmaxf((float)deg[t], 1.0f));
        atomicAdd(&out[(size_t)t * D + d], ns * nt * x[(size_t)s * D + d]);
    }
}

// ---------------- tiny-ws / big-n fallback (round-1 proven) ----------------

__global__ void fb_hist(const int* __restrict__ src, int* __restrict__ deg, int E) {
    int e = blockIdx.x * blockDim.x + threadIdx.x;
    if (e < E) atomicAdd(&deg[src[e]], 1);
}
__global__ void fb_norm(const int* __restrict__ deg, float* __restrict__ norm, int n) {
    int i = blockIdx.x * blockDim.x + threadIdx.x;
    if (i < n) norm[i] = rsqrtf(fmaxf((float)deg[i], 1.0f));
}
__global__ void fb_init_out(const float4* __restrict__ x, float4* __restrict__ out, int n4) {
    int i = blockIdx.x * blockDim.x + threadIdx.x;
    if (i < n4) {
        float4 v = x[i];
        out[i] = make_float4(v.x * EPS, v.y * EPS, v.z * EPS, v.w * EPS);
    }
}
__global__ void fb_scatter(const float* __restrict__ x, const int* __restrict__ src,
                           const int* __restrict__ dst, const float* __restrict__ norm,
                           float* __restrict__ out, int E) {
    long long tid = (long long)blockIdx.x * blockDim.x + threadIdx.x;
    int e = (int)(tid >> 6), d = (int)(tid & 63);
    if (e < E) {
        int s = src[e], t = dst[e];
        atomicAdd(&out[(size_t)t * D + d], norm[s] * norm[t] * x[(size_t)s * D + d]);
    }
}

// ---------------- launcher ----------------

extern "C" void kernel_launch(void* const* d_in, const int* in_sizes, int n_in,
                              void* d_out, int out_size, void* d_ws, size_t ws_size,
                              hipStream_t stream) {
    const float* x   = (const float*)d_in[0];
    const int*   src = (const int*)d_in[1];
    const int*   dst = (const int*)d_in[2];
    float* out = (float*)d_out;

    const int ND = in_sizes[0];
    const int E  = in_sizes[1];
    const int n  = ND / D;
    const int NB = (n + BKT - 1) / BKT;
    constexpr int B = 256;
    const int NB64 = (NB + 63) & ~63;

    int capb = 0;
    for (int c : {4096, 3584}) {               // both divisible by 16 (uint4 align of yh)
        size_t need = (size_t)NB * c * 4                // rec (packed u32)
                    + (size_t)ND * 2                    // yh
                    + (size_t)n * 4                     // deg
                    + (size_t)NB64 * 4                  // curD
                    + (size_t)64 * 4                    // ovf_cnt
                    + (size_t)2 * MAXOVF * 4;           // ovf
        if (need <= ws_size) { capb = c; break; }
    }

    if (NB <= NBMAX && capb > 0 && n < (1 << 24)) {
        unsigned int* rec = (unsigned int*)d_ws;                         // NB*capb u32
        unsigned int* yh  = rec + (size_t)NB * capb;                     // ND/2 u32
        int* deg          = (int*)(yh + ND / 2);                         // n
        int* curD         = deg + n;                                     // NB64
        int* ovf_cnt      = curD + NB64;                                 // 64
        int* ovf          = ovf_cnt + 64;                                // 2*MAXOVF

        // deg + curD + ovf_cnt zeroed in one DMA memset
        hipMemsetAsync(deg, 0, (size_t)(n + NB64 + 64) * 4, stream);
        partition_kernel<<<(E + EPB - 1) / EPB, PTHREADS, 0, stream>>>(src, dst, curD, rec, deg,
                                                                       ovf_cnt, ovf, E, NB, capb);
        normyh_kernel<<<NB, B, 0, stream>>>(deg, (const float2*)x, yh, n);
        sortgather_kernel<<<NB, 512, 0, stream>>>(rec, curD, deg, (const uint4*)yh,
                                                  (const float4*)x, (float4*)out, n, capb);
        cleanup_kernel<<<32, B, 0, stream>>>(x, deg, ovf_cnt, ovf, out);
    } else {
        int*   deg  = (int*)d_ws;
        float* norm = (float*)d_ws + n;
        hipMemsetAsync(deg, 0, (size_t)n * sizeof(int), stream);
        fb_hist<<<(E + B - 1) / B, B, 0, stream>>>(src, deg, E);
        fb_norm<<<(n + B - 1) / B, B, 0, stream>>>(deg, norm, n);
        fb_init_out<<<(ND / 4 + B - 1) / B, B, 0, stream>>>((const float4*)x, (float4*)out, ND / 4);
        long long total = (long long)E * D;
        fb_scatter<<<(int)((total + B - 1) / B), B, 0, stream>>>(x, src, dst, norm, out, E);
    }
}

// Round 3
// 146.114 us; speedup vs baseline: 1.2660x; 1.2393x over previous
//
#include <hip/hip_runtime.h>

// GCN aggregation: out[t] = norm[t] * sum_{e:dst=t} norm[src]*x[src] + EPS*x[t]
// Round 12: kill per-edge global atomics. Round 11's WRITE_SIZE (45 MB) was
// dominated by atomicAdd(&deg[src],1): 1.25M device-scope atomics execute past
// the per-XCD L2 (~32B EA traffic each ~= 40 MB). Out-degree goes back to the
// bucketed byte-scatter (srec) + per-bucket LDS histogram, now at BKT=256 /
// EPB=8192 geometry (~21B fragments, so srec write-amp is small). normyh
// computes hist -> norm[] -> yh per bucket. sortgather: 1024 threads (16
// waves), grid NB=391 was occupancy-starved at 512. No deg array.
// 3 main launches + cleanup + 1 tiny memset.
constexpr int D        = 64;
constexpr float EPS    = 0.5f;
constexpr int BKT      = 256;    // nodes per bucket
constexpr int CAPB_MAX = 4096;
constexpr int EPB      = 8192;   // edges per partition block
constexpr int PTHREADS = 512;
constexpr int EPT      = EPB / PTHREADS;   // 16 edges per thread
constexpr int GTHREADS = 1024;   // sortgather block size
constexpr int NBMAX    = 1024;
constexpr int MAXOVF   = 65536;

__device__ __forceinline__ unsigned int f2bf(float f) {
    unsigned int u = __float_as_uint(f);
    return (u + 0x7FFFu + ((u >> 16) & 1u)) >> 16;   // RNE to bf16
}
__device__ __forceinline__ float bf2f_lo(unsigned int v) { return __uint_as_float(v << 16); }
__device__ __forceinline__ float bf2f_hi(unsigned int v) { return __uint_as_float(v & 0xFFFF0000u); }

// ---------------- main path ----------------

__global__ __launch_bounds__(PTHREADS)
void partition_kernel(const int* __restrict__ src, const int* __restrict__ dst,
                      int* __restrict__ curD, int* __restrict__ curS,
                      unsigned int* __restrict__ rec, unsigned char* __restrict__ srec,
                      int* __restrict__ ovf_cnt, int* __restrict__ ovf,
                      int* __restrict__ sovf_cnt, int* __restrict__ sovf,
                      int E, int NB, int capb) {
    __shared__ int histD[NBMAX];   // then reused as rank
    __shared__ int histS[NBMAX];
    __shared__ int startD[NBMAX];
    __shared__ int startS[NBMAX];
    const int base = blockIdx.x * EPB;
    const int tid  = threadIdx.x;
    for (int b = tid; b < NB; b += PTHREADS) { histD[b] = 0; histS[b] = 0; }
    __syncthreads();

    int se[EPT], te[EPT];
    #pragma unroll
    for (int k = 0; k < EPT; ++k) {
        int e = base + tid + k * PTHREADS;     // coalesced
        se[k] = -1;
        if (e < E) {
            int s = src[e], t = dst[e];
            se[k] = s; te[k] = t;
            atomicAdd(&histD[t >> 8], 1);      // LDS only
            atomicAdd(&histS[s >> 8], 1);      // LDS only
        }
    }
    __syncthreads();
    for (int b = tid; b < NB; b += PTHREADS) { // one global reserve atomic per (block,bucket)
        int c = histD[b];
        startD[b] = (c > 0) ? atomicAdd(&curD[b], c) : 0;
        histD[b] = 0;                          // reuse as rank
        int c2 = histS[b];
        startS[b] = (c2 > 0) ? atomicAdd(&curS[b], c2) : 0;
        histS[b] = 0;
    }
    __syncthreads();
    #pragma unroll
    for (int k = 0; k < EPT; ++k) {
        if (se[k] >= 0) {
            int s = se[k], t = te[k];
            int bD = t >> 8;
            int r  = atomicAdd(&histD[bD], 1);
            int p  = startD[bD] + r;           // zero-based within bucket
            if (p < capb) {
                rec[(size_t)bD * capb + p] = ((unsigned int)s << 8) | (unsigned int)(t & (BKT - 1));
            } else {
                int i = atomicAdd(ovf_cnt, 1);
                if (i < MAXOVF) { ovf[2 * i] = s; ovf[2 * i + 1] = t; }
            }
            int bS = s >> 8;
            int r2 = atomicAdd(&histS[bS], 1);
            int p2 = startS[bS] + r2;
            if (p2 < capb) {
                srec[(size_t)bS * capb + p2] = (unsigned char)(s & (BKT - 1));
            } else {
                int i = atomicAdd(sovf_cnt, 1);
                if (i < MAXOVF) sovf[i] = s;
            }
        }
    }
}

// Per-bucket: out-degree histogram from srec bytes -> norm[] -> yh = bf16(norm*x).
// Must complete before any gather reads yh (separate launch).
__global__ __launch_bounds__(256)
void normyh_kernel(const unsigned char* __restrict__ srec, const int* __restrict__ curS,
                   const int* __restrict__ sovf_cnt, const int* __restrict__ sovf,
                   const float2* __restrict__ x2, unsigned int* __restrict__ yh,
                   float* __restrict__ norm, int n, int capb) {
    const int b   = blockIdx.x;
    const int tid = threadIdx.x;
    __shared__ int hist[BKT];
    __shared__ float nrm[BKT];
    hist[tid] = 0;                             // BKT == blockDim == 256
    __syncthreads();
    int cnt = curS[b];
    if (cnt > capb) cnt = capb;
    const unsigned int* s4 = (const unsigned int*)(srec + (size_t)b * capb);  // capb % 4 == 0
    int nw = cnt >> 2;
    for (int i = tid; i < nw; i += 256) {      // word-wise coalesced
        unsigned int w = s4[i];
        atomicAdd(&hist[w & 255u], 1);
        atomicAdd(&hist[(w >> 8) & 255u], 1);
        atomicAdd(&hist[(w >> 16) & 255u], 1);
        atomicAdd(&hist[w >> 24], 1);
    }
    for (int i = (nw << 2) + tid; i < cnt; i += 256)
        atomicAdd(&hist[srec[(size_t)b * capb + i]], 1);
    int oc = *sovf_cnt;                        // expected 0
    if (oc > 0) {
        if (oc > MAXOVF) oc = MAXOVF;
        for (int i = tid; i < oc; i += 256) {
            int s = sovf[i];
            if ((s >> 8) == b) atomicAdd(&hist[s & (BKT - 1)], 1);
        }
    }
    __syncthreads();
    int node = b * BKT + tid;
    float nm = rsqrtf(fmaxf((float)hist[tid], 1.0f));
    nrm[tid] = nm;
    if (node < n) norm[node] = nm;
    __syncthreads();
    int nodes = n - b * BKT;
    if (nodes > BKT) nodes = BKT;
    if (nodes < 0) nodes = 0;
    int total = nodes * (D / 2);               // float2 elements in this bucket
    size_t gbase = (size_t)b * BKT * (D / 2);
    for (int i = tid; i < total; i += 256) {   // contiguous -> coalesced
        float2 v = x2[gbase + i];
        float nm2 = nrm[i >> 5];
        yh[gbase + i] = f2bf(v.x * nm2) | (f2bf(v.y * nm2) << 16);
    }
}

// One block per bucket (1024 threads = 16 waves). Phase 1: LDS counting sort of
// the bucket's dst-records -> per-node src lists in LDS. Phase 2: gather, 8
// nodes per wave (8 lanes x uint4 = 128B yh row), src indices read from LDS
// (short dependent chain), 8-deep unroll for memory-level parallelism.
__global__ __launch_bounds__(GTHREADS)
void sortgather_kernel(const unsigned int* __restrict__ rec, const int* __restrict__ curD,
                       const float* __restrict__ norm, const uint4* __restrict__ yr4,
                       const float4* __restrict__ x4, float4* __restrict__ out4,
                       int n, int capb) {
    __shared__ unsigned int recs[CAPB_MAX];   // 16 KB
    __shared__ int srcs[CAPB_MAX];            // 16 KB
    __shared__ int hist[BKT];                 // per-node in-count (pristine after scan)
    __shared__ int scanv[BKT];
    __shared__ int rankb[BKT];
    __shared__ int rsL[BKT];                  // per-node exclusive start (pristine)
    __shared__ float nrmL[BKT];               // per-node dst norm
    const int b   = blockIdx.x;
    const int tid = threadIdx.x;

    int cnt = curD[b];
    if (cnt > capb) cnt = capb;
    for (int i = tid; i < cnt; i += GTHREADS) recs[i] = rec[(size_t)b * capb + i];
    if (tid < BKT) {
        hist[tid] = 0;
        int node = b * BKT + tid;
        nrmL[tid] = (node < n) ? norm[node] : 1.0f;
    }
    __syncthreads();
    for (int i = tid; i < cnt; i += GTHREADS) atomicAdd(&hist[recs[i] & (BKT - 1)], 1);
    __syncthreads();
    if (tid < BKT) scanv[tid] = hist[tid];
    __syncthreads();
    #pragma unroll
    for (int off = 1; off < BKT; off <<= 1) {          // Hillis-Steele inclusive scan
        int t = 0;
        if (tid < BKT && tid >= off) t = scanv[tid - off];
        __syncthreads();
        if (tid < BKT) scanv[tid] += t;
        __syncthreads();
    }
    if (tid < BKT) {
        int excl = scanv[tid] - hist[tid];
        rankb[tid] = excl;
        rsL[tid]   = excl;
    }
    __syncthreads();
    for (int i = tid; i < cnt; i += GTHREADS) {
        unsigned int v = recs[i];
        int pos = atomicAdd(&rankb[v & (BKT - 1)], 1);
        srcs[pos] = (int)(v >> 8);
    }
    __syncthreads();

    // ---- gather phase ----
    const int wave = tid >> 6;                 // 0..15
    const int lane = tid & 63;
    const int fl   = lane & 7;                 // uint4 index within 128B row
    const int oct  = lane >> 3;                // 0..7 -> node within group
    #pragma unroll
    for (int r = 0; r < BKT / 128; ++r) {      // 2 rounds of 128 nodes
        int ln   = r * 128 + wave * 8 + oct;   // local node 0..255
        int node = b * BKT + ln;
        bool valid = node < n;
        int rsl = valid ? rsL[ln]  : 0;
        int cl  = valid ? hist[ln] : 0;
        int m = cl;                            // uniform loop count = wave-max
        m = max(m, __shfl_xor(m, 8));
        m = max(m, __shfl_xor(m, 16));
        m = max(m, __shfl_xor(m, 32));
        float a0 = 0.f, a1 = 0.f, a2 = 0.f, a3 = 0.f;
        float a4 = 0.f, a5 = 0.f, a6 = 0.f, a7 = 0.f;
        for (int k = 0; k < m; k += 8) {
            int sb[8];
            #pragma unroll
            for (int j = 0; j < 8; ++j) {      // 8 LDS reads issue together
                int kj = k + j;
                sb[j] = (kj < cl) ? srcs[rsl + kj] : -1;
            }
            #pragma unroll
            for (int j = 0; j < 8; ++j) {      // 8 row loads in flight
                bool take = sb[j] >= 0;
                int s = take ? sb[j] : 0;      // dummy hits node 0's cached row
                uint4 v = yr4[(size_t)s * 8 + fl];
                if (!take) { v.x = 0u; v.y = 0u; v.z = 0u; v.w = 0u; }
                a0 += bf2f_lo(v.x); a1 += bf2f_hi(v.x);
                a2 += bf2f_lo(v.y); a3 += bf2f_hi(v.y);
                a4 += bf2f_lo(v.z); a5 += bf2f_hi(v.z);
                a6 += bf2f_lo(v.w); a7 += bf2f_hi(v.w);
            }
        }
        if (valid) {
            float nt = nrmL[ln];
            size_t basei = (size_t)node * 16 + fl * 2;
            float4 xv0 = x4[basei], xv1 = x4[basei + 1];
            float4 r0, r1;
            r0.x = a0 * nt + EPS * xv0.x;  r0.y = a1 * nt + EPS * xv0.y;
            r0.z = a2 * nt + EPS * xv0.z;  r0.w = a3 * nt + EPS * xv0.w;
            r1.x = a4 * nt + EPS * xv1.x;  r1.y = a5 * nt + EPS * xv1.y;
            r1.z = a6 * nt + EPS * xv1.z;  r1.w = a7 * nt + EPS * xv1.w;
            out4[basei] = r0;              // coalesced: 32B/lane, 256B per oct
            out4[basei + 1] = r1;
        }
    }
}

// rare: dst-bucket overflow edges (expected 0)
__global__ void cleanup_kernel(const float* __restrict__ x, const float* __restrict__ norm,
                               const int* __restrict__ ovf_cnt, const int* __restrict__ ovf,
                               float* __restrict__ out) {
    int cnt = *ovf_cnt;
    if (cnt > MAXOVF) cnt = MAXOVF;
    long long total = (long long)cnt * D;
    long long stride = (long long)gridDim.x * blockDim.x;
    for (long long i = blockIdx.x * (long long)blockDim.x + threadIdx.x; i < total; i += stride) {
        int e = (int)(i >> 6), d = (int)(i & 63);
        int s = ovf[2 * e], t = ovf[2 * e + 1];
        atomicAdd(&out[(size_t)t * D + d], norm[s] * norm[t] * x[(size_t)s * D + d]);
    }
}

// ---------------- tiny-ws / big-n fallback (round-1 proven) ----------------

__global__ void fb_hist(const int* __restrict__ src, int* __restrict__ deg, int E) {
    int e = blockIdx.x * blockDim.x + threadIdx.x;
    if (e < E) atomicAdd(&deg[src[e]], 1);
}
__global__ void fb_norm(const int* __restrict__ deg, float* __restrict__ norm, int n) {
    int i = blockIdx.x * blockDim.x + threadIdx.x;
    if (i < n) norm[i] = rsqrtf(fmaxf((float)deg[i], 1.0f));
}
__global__ void fb_init_out(const float4* __restrict__ x, float4* __restrict__ out, int n4) {
    int i = blockIdx.x * blockDim.x + threadIdx.x;
    if (i < n4) {
        float4 v = x[i];
        out[i] = make_float4(v.x * EPS, v.y * EPS, v.z * EPS, v.w * EPS);
    }
}
__global__ void fb_scatter(const float* __restrict__ x, const int* __restrict__ src,
                           const int* __restrict__ dst, const float* __restrict__ norm,
                           float* __restrict__ out, int E) {
    long long tid = (long long)blockIdx.x * blockDim.x + threadIdx.x;
    int e = (int)(tid >> 6), d = (int)(tid & 63);
    if (e < E) {
        int s = src[e], t = dst[e];
        atomicAdd(&out[(size_t)t * D + d], norm[s] * norm[t] * x[(size_t)s * D + d]);
    }
}

// ---------------- launcher ----------------

extern "C" void kernel_launch(void* const* d_in, const int* in_sizes, int n_in,
                              void* d_out, int out_size, void* d_ws, size_t ws_size,
                              hipStream_t stream) {
    const float* x   = (const float*)d_in[0];
    const int*   src = (const int*)d_in[1];
    const int*   dst = (const int*)d_in[2];
    float* out = (float*)d_out;

    const int ND = in_sizes[0];
    const int E  = in_sizes[1];
    const int n  = ND / D;
    const int NB = (n + BKT - 1) / BKT;
    constexpr int B = 256;
    const int NB64 = (NB + 63) & ~63;

    int capb = 0;
    for (int c : {4096, 3584}) {               // divisible by 16
        size_t srecB = ((size_t)NB * c + 15) & ~15ull;
        size_t need = (size_t)NB * c * 4                // rec (packed u32)
                    + srecB                             // srec (u8)
                    + (size_t)ND * 2                    // yh
                    + (size_t)n * 4                     // norm
                    + (size_t)(2 * NB64 + 128) * 4      // curD, curS, ovf_cnt, sovf_cnt
                    + (size_t)3 * MAXOVF * 4;           // ovf + sovf
        if (need <= ws_size) { capb = c; break; }
    }

    if (NB <= NBMAX && capb > 0 && n < (1 << 24)) {
        unsigned int* rec   = (unsigned int*)d_ws;                        // NB*capb u32
        unsigned char* srec = (unsigned char*)(rec + (size_t)NB * capb);  // NB*capb u8
        size_t srecB        = ((size_t)NB * capb + 15) & ~15ull;
        unsigned int* yh    = (unsigned int*)(srec + srecB);              // ND/2 u32
        float* norm         = (float*)(yh + ND / 2);                      // n
        int* curD           = (int*)(norm + n);                           // NB64
        int* curS           = curD + NB64;                                // NB64
        int* ovf_cnt        = curS + NB64;                                // 64
        int* sovf_cnt       = ovf_cnt + 64;                               // 64
        int* ovf            = sovf_cnt + 64;                              // 2*MAXOVF
        int* sovf           = ovf + 2 * MAXOVF;                           // MAXOVF

        // curD + curS + ovf_cnt + sovf_cnt zeroed in one DMA memset
        hipMemsetAsync(curD, 0, (size_t)(2 * NB64 + 128) * 4, stream);
        partition_kernel<<<(E + EPB - 1) / EPB, PTHREADS, 0, stream>>>(src, dst, curD, curS,
                                                                       rec, srec, ovf_cnt, ovf,
                                                                       sovf_cnt, sovf, E, NB, capb);
        normyh_kernel<<<NB, B, 0, stream>>>(srec, curS, sovf_cnt, sovf,
                                            (const float2*)x, yh, norm, n, capb);
        sortgather_kernel<<<NB, GTHREADS, 0, stream>>>(rec, curD, norm, (const uint4*)yh,
                                                       (const float4*)x, (float4*)out, n, capb);
        cleanup_kernel<<<32, B, 0, stream>>>(x, norm, ovf_cnt, ovf, out);
    } else {
        int*   deg  = (int*)d_ws;
        float* norm = (float*)d_ws + n;
        hipMemsetAsync(deg, 0, (size_t)n * sizeof(int), stream);
        fb_hist<<<(E + B - 1) / B, B, 0, stream>>>(src, deg, E);
        fb_norm<<<(n + B - 1) / B, B, 0, stream>>>(deg, norm, n);
        fb_init_out<<<(ND / 4 + B - 1) / B, B, 0, stream>>>((const float4*)x, (float4*)out, ND / 4);
        long long total = (long long)E * D;
        fb_scatter<<<(int)((total + B - 1) / B), B, 0, stream>>>(x, src, dst, norm, out, E);
    }
}

// Round 4
// 140.701 us; speedup vs baseline: 1.3147x; 1.0385x over previous
//
#include <hip/hip_runtime.h>

// GCN aggregation: out[t] = norm[t] * sum_{e:dst=t} norm[src]*x[src] + EPS*x[t]
// Round 13: partition scratch-spill fix. Rounds 11-12 stashed 16 (s,t) pairs in
// "registers" (32 VGPR needed, VGPR_Count=24 reported -> spilled to scratch =
// ~20 MB of hidden HBM traffic per launch). Fix: no stash; pass 3 re-reads
// src/dst (coalesced, L2-resident between passes). int4 loads on full blocks.
// sortgather: Hillis-Steele scan (17 barriers x 16 waves) -> per-wave shfl_up
// scan + cross-wave fixup (2 barriers).
// 3 main launches + cleanup + 1 tiny memset.
constexpr int D        = 64;
constexpr float EPS    = 0.5f;
constexpr int BKT      = 256;    // nodes per bucket
constexpr int CAPB_MAX = 4096;
constexpr int EPB      = 8192;   // edges per partition block
constexpr int PTHREADS = 512;
constexpr int EPT      = EPB / PTHREADS;   // 16 edges per thread
constexpr int GTHREADS = 1024;   // sortgather block size
constexpr int NBMAX    = 1024;
constexpr int MAXOVF   = 65536;

__device__ __forceinline__ unsigned int f2bf(float f) {
    unsigned int u = __float_as_uint(f);
    return (u + 0x7FFFu + ((u >> 16) & 1u)) >> 16;   // RNE to bf16
}
__device__ __forceinline__ float bf2f_lo(unsigned int v) { return __uint_as_float(v << 16); }
__device__ __forceinline__ float bf2f_hi(unsigned int v) { return __uint_as_float(v & 0xFFFF0000u); }

// ---------------- main path ----------------

__global__ __launch_bounds__(PTHREADS)
void partition_kernel(const int* __restrict__ src, const int* __restrict__ dst,
                      int* __restrict__ curD, int* __restrict__ curS,
                      unsigned int* __restrict__ rec, unsigned char* __restrict__ srec,
                      int* __restrict__ ovf_cnt, int* __restrict__ ovf,
                      int* __restrict__ sovf_cnt, int* __restrict__ sovf,
                      int E, int NB, int capb) {
    __shared__ int histD[NBMAX];   // then reused as rank
    __shared__ int histS[NBMAX];
    __shared__ int startD[NBMAX];
    __shared__ int startS[NBMAX];
    const int base = blockIdx.x * EPB;
    const int tid  = threadIdx.x;
    const bool full = (base + EPB) <= E;
    for (int b = tid; b < NB; b += PTHREADS) { histD[b] = 0; histS[b] = 0; }
    __syncthreads();

    // ---- pass 1: count ----
    if (full) {
        const int4* s4 = (const int4*)(src + base);
        const int4* d4 = (const int4*)(dst + base);
        #pragma unroll
        for (int k = 0; k < EPT / 4; ++k) {
            int4 sv = s4[tid + k * PTHREADS];
            int4 dv = d4[tid + k * PTHREADS];
            atomicAdd(&histD[dv.x >> 8], 1); atomicAdd(&histS[sv.x >> 8], 1);
            atomicAdd(&histD[dv.y >> 8], 1); atomicAdd(&histS[sv.y >> 8], 1);
            atomicAdd(&histD[dv.z >> 8], 1); atomicAdd(&histS[sv.z >> 8], 1);
            atomicAdd(&histD[dv.w >> 8], 1); atomicAdd(&histS[sv.w >> 8], 1);
        }
    } else {
        for (int k = 0; k < EPT; ++k) {
            int e = base + tid + k * PTHREADS;
            if (e < E) {
                atomicAdd(&histD[dst[e] >> 8], 1);
                atomicAdd(&histS[src[e] >> 8], 1);
            }
        }
    }
    __syncthreads();
    // ---- reserve: one global atomic per (block,bucket) ----
    for (int b = tid; b < NB; b += PTHREADS) {
        int c = histD[b];
        startD[b] = (c > 0) ? atomicAdd(&curD[b], c) : 0;
        histD[b] = 0;                          // reuse as rank
        int c2 = histS[b];
        startS[b] = (c2 > 0) ? atomicAdd(&curS[b], c2) : 0;
        histS[b] = 0;
    }
    __syncthreads();
    // ---- pass 2: place (re-read src/dst; L2-resident) ----
    if (full) {
        const int4* s4 = (const int4*)(src + base);
        const int4* d4 = (const int4*)(dst + base);
        #pragma unroll
        for (int k = 0; k < EPT / 4; ++k) {
            int4 sv = s4[tid + k * PTHREADS];
            int4 dv = d4[tid + k * PTHREADS];
            int ss[4] = {sv.x, sv.y, sv.z, sv.w};
            int tt[4] = {dv.x, dv.y, dv.z, dv.w};
            #pragma unroll
            for (int j = 0; j < 4; ++j) {
                int s = ss[j], t = tt[j];
                int bD = t >> 8;
                int r  = atomicAdd(&histD[bD], 1);
                int p  = startD[bD] + r;
                if (p < capb) {
                    rec[(size_t)bD * capb + p] = ((unsigned int)s << 8) | (unsigned int)(t & (BKT - 1));
                } else {
                    int i = atomicAdd(ovf_cnt, 1);
                    if (i < MAXOVF) { ovf[2 * i] = s; ovf[2 * i + 1] = t; }
                }
                int bS = s >> 8;
                int r2 = atomicAdd(&histS[bS], 1);
                int p2 = startS[bS] + r2;
                if (p2 < capb) {
                    srec[(size_t)bS * capb + p2] = (unsigned char)(s & (BKT - 1));
                } else {
                    int i = atomicAdd(sovf_cnt, 1);
                    if (i < MAXOVF) sovf[i] = s;
                }
            }
        }
    } else {
        for (int k = 0; k < EPT; ++k) {
            int e = base + tid + k * PTHREADS;
            if (e < E) {
                int s = src[e], t = dst[e];
                int bD = t >> 8;
                int r  = atomicAdd(&histD[bD], 1);
                int p  = startD[bD] + r;
                if (p < capb) {
                    rec[(size_t)bD * capb + p] = ((unsigned int)s << 8) | (unsigned int)(t & (BKT - 1));
                } else {
                    int i = atomicAdd(ovf_cnt, 1);
                    if (i < MAXOVF) { ovf[2 * i] = s; ovf[2 * i + 1] = t; }
                }
                int bS = s >> 8;
                int r2 = atomicAdd(&histS[bS], 1);
                int p2 = startS[bS] + r2;
                if (p2 < capb) {
                    srec[(size_t)bS * capb + p2] = (unsigned char)(s & (BKT - 1));
                } else {
                    int i = atomicAdd(sovf_cnt, 1);
                    if (i < MAXOVF) sovf[i] = s;
                }
            }
        }
    }
}

// Per-bucket: out-degree histogram from srec bytes -> norm[] -> yh = bf16(norm*x).
// Must complete before any gather reads yh (separate launch).
__global__ __launch_bounds__(256)
void normyh_kernel(const unsigned char* __restrict__ srec, const int* __restrict__ curS,
                   const int* __restrict__ sovf_cnt, const int* __restrict__ sovf,
                   const float2* __restrict__ x2, unsigned int* __restrict__ yh,
                   float* __restrict__ norm, int n, int capb) {
    const int b   = blockIdx.x;
    const int tid = threadIdx.x;
    __shared__ int hist[BKT];
    __shared__ float nrm[BKT];
    hist[tid] = 0;                             // BKT == blockDim == 256
    __syncthreads();
    int cnt = curS[b];
    if (cnt > capb) cnt = capb;
    const unsigned int* s4 = (const unsigned int*)(srec + (size_t)b * capb);  // capb % 4 == 0
    int nw = cnt >> 2;
    for (int i = tid; i < nw; i += 256) {      // word-wise coalesced
        unsigned int w = s4[i];
        atomicAdd(&hist[w & 255u], 1);
        atomicAdd(&hist[(w >> 8) & 255u], 1);
        atomicAdd(&hist[(w >> 16) & 255u], 1);
        atomicAdd(&hist[w >> 24], 1);
    }
    for (int i = (nw << 2) + tid; i < cnt; i += 256)
        atomicAdd(&hist[srec[(size_t)b * capb + i]], 1);
    int oc = *sovf_cnt;                        // expected 0
    if (oc > 0) {
        if (oc > MAXOVF) oc = MAXOVF;
        for (int i = tid; i < oc; i += 256) {
            int s = sovf[i];
            if ((s >> 8) == b) atomicAdd(&hist[s & (BKT - 1)], 1);
        }
    }
    __syncthreads();
    int node = b * BKT + tid;
    float nm = rsqrtf(fmaxf((float)hist[tid], 1.0f));
    nrm[tid] = nm;
    if (node < n) norm[node] = nm;
    __syncthreads();
    int nodes = n - b * BKT;
    if (nodes > BKT) nodes = BKT;
    if (nodes < 0) nodes = 0;
    int total = nodes * (D / 2);               // float2 elements in this bucket
    size_t gbase = (size_t)b * BKT * (D / 2);
    for (int i = tid; i < total; i += 256) {   // contiguous -> coalesced
        float2 v = x2[gbase + i];
        float nm2 = nrm[i >> 5];
        yh[gbase + i] = f2bf(v.x * nm2) | (f2bf(v.y * nm2) << 16);
    }
}

// One block per bucket (1024 threads = 16 waves). Phase 1: LDS counting sort of
// the bucket's dst-records -> per-node src lists in LDS. Phase 2: gather, 8
// nodes per wave (8 lanes x uint4 = 128B yh row), src indices read from LDS
// (short dependent chain), 8-deep unroll for memory-level parallelism.
__global__ __launch_bounds__(GTHREADS)
void sortgather_kernel(const unsigned int* __restrict__ rec, const int* __restrict__ curD,
                       const float* __restrict__ norm, const uint4* __restrict__ yr4,
                       const float4* __restrict__ x4, float4* __restrict__ out4,
                       int n, int capb) {
    __shared__ unsigned int recs[CAPB_MAX];   // 16 KB
    __shared__ int srcs[CAPB_MAX];            // 16 KB
    __shared__ int hist[BKT];                 // per-node in-count (pristine after scan)
    __shared__ int rankb[BKT];
    __shared__ int rsL[BKT];                  // per-node exclusive start (pristine)
    __shared__ float nrmL[BKT];               // per-node dst norm
    __shared__ int wsum[BKT / 64];
    const int b   = blockIdx.x;
    const int tid = threadIdx.x;

    int cnt = curD[b];
    if (cnt > capb) cnt = capb;
    for (int i = tid; i < cnt; i += GTHREADS) recs[i] = rec[(size_t)b * capb + i];
    if (tid < BKT) {
        hist[tid] = 0;
        int node = b * BKT + tid;
        nrmL[tid] = (node < n) ? norm[node] : 1.0f;
    }
    __syncthreads();
    for (int i = tid; i < cnt; i += GTHREADS) atomicAdd(&hist[recs[i] & (BKT - 1)], 1);
    __syncthreads();
    // ---- per-wave shfl inclusive scan over hist[0..BKT) (threads 0..BKT-1) ----
    {
        const int lane = tid & 63;
        int v = (tid < BKT) ? hist[tid] : 0;
        #pragma unroll
        for (int off = 1; off < 64; off <<= 1) {
            int t = __shfl_up(v, off);
            if (lane >= off) v += t;
        }
        if (tid < BKT && lane == 63) wsum[tid >> 6] = v;
        __syncthreads();
        if (tid < BKT) {
            int w = tid >> 6, add = 0;
            #pragma unroll
            for (int i = 0; i < BKT / 64; ++i)
                if (i < w) add += wsum[i];
            int excl = v + add - hist[tid];
            rankb[tid] = excl;
            rsL[tid]   = excl;
        }
    }
    __syncthreads();
    for (int i = tid; i < cnt; i += GTHREADS) {
        unsigned int v = recs[i];
        int pos = atomicAdd(&rankb[v & (BKT - 1)], 1);
        srcs[pos] = (int)(v >> 8);
    }
    __syncthreads();

    // ---- gather phase ----
    const int wave = tid >> 6;                 // 0..15
    const int lane = tid & 63;
    const int fl   = lane & 7;                 // uint4 index within 128B row
    const int oct  = lane >> 3;                // 0..7 -> node within group
    #pragma unroll
    for (int r = 0; r < BKT / 128; ++r) {      // 2 rounds of 128 nodes
        int ln   = r * 128 + wave * 8 + oct;   // local node 0..255
        int node = b * BKT + ln;
        bool valid = node < n;
        int rsl = valid ? rsL[ln]  : 0;
        int cl  = valid ? hist[ln] : 0;
        int m = cl;                            // uniform loop count = wave-max
        m = max(m, __shfl_xor(m, 8));
        m = max(m, __shfl_xor(m, 16));
        m = max(m, __shfl_xor(m, 32));
        float a0 = 0.f, a1 = 0.f, a2 = 0.f, a3 = 0.f;
        float a4 = 0.f, a5 = 0.f, a6 = 0.f, a7 = 0.f;
        for (int k = 0; k < m; k += 8) {
            int sb[8];
            #pragma unroll
            for (int j = 0; j < 8; ++j) {      // 8 LDS reads issue together
                int kj = k + j;
                sb[j] = (kj < cl) ? srcs[rsl + kj] : -1;
            }
            #pragma unroll
            for (int j = 0; j < 8; ++j) {      // 8 row loads in flight
                bool take = sb[j] >= 0;
                int s = take ? sb[j] : 0;      // dummy hits node 0's cached row
                uint4 v = yr4[(size_t)s * 8 + fl];
                if (!take) { v.x = 0u; v.y = 0u; v.z = 0u; v.w = 0u; }
                a0 += bf2f_lo(v.x); a1 += bf2f_hi(v.x);
                a2 += bf2f_lo(v.y); a3 += bf2f_hi(v.y);
                a4 += bf2f_lo(v.z); a5 += bf2f_hi(v.z);
                a6 += bf2f_lo(v.w); a7 += bf2f_hi(v.w);
            }
        }
        if (valid) {
            float nt = nrmL[ln];
            size_t basei = (size_t)node * 16 + fl * 2;
            float4 xv0 = x4[basei], xv1 = x4[basei + 1];
            float4 r0, r1;
            r0.x = a0 * nt + EPS * xv0.x;  r0.y = a1 * nt + EPS * xv0.y;
            r0.z = a2 * nt + EPS * xv0.z;  r0.w = a3 * nt + EPS * xv0.w;
            r1.x = a4 * nt + EPS * xv1.x;  r1.y = a5 * nt + EPS * xv1.y;
            r1.z = a6 * nt + EPS * xv1.z;  r1.w = a7 * nt + EPS * xv1.w;
            out4[basei] = r0;              // coalesced: 32B/lane, 256B per oct
            out4[basei + 1] = r1;
        }
    }
}

// rare: dst-bucket overflow edges (expected 0)
__global__ void cleanup_kernel(const float* __restrict__ x, const float* __restrict__ norm,
                               const int* __restrict__ ovf_cnt, const int* __restrict__ ovf,
                               float* __restrict__ out) {
    int cnt = *ovf_cnt;
    if (cnt > MAXOVF) cnt = MAXOVF;
    long long total = (long long)cnt * D;
    long long stride = (long long)gridDim.x * blockDim.x;
    for (long long i = blockIdx.x * (long long)blockDim.x + threadIdx.x; i < total; i += stride) {
        int e = (int)(i >> 6), d = (int)(i & 63);
        int s = ovf[2 * e], t = ovf[2 * e + 1];
        atomicAdd(&out[(size_t)t * D + d], norm[s] * norm[t] * x[(size_t)s * D + d]);
    }
}

// ---------------- tiny-ws / big-n fallback (round-1 proven) ----------------

__global__ void fb_hist(const int* __restrict__ src, int* __restrict__ deg, int E) {
    int e = blockIdx.x * blockDim.x + threadIdx.x;
    if (e < E) atomicAdd(&deg[src[e]], 1);
}
__global__ void fb_norm(const int* __restrict__ deg, float* __restrict__ norm, int n) {
    int i = blockIdx.x * blockDim.x + threadIdx.x;
    if (i < n) norm[i] = rsqrtf(fmaxf((float)deg[i], 1.0f));
}
__global__ void fb_init_out(const float4* __restrict__ x, float4* __restrict__ out, int n4) {
    int i = blockIdx.x * blockDim.x + threadIdx.x;
    if (i < n4) {
        float4 v = x[i];
        out[i] = make_float4(v.x * EPS, v.y * EPS, v.z * EPS, v.w * EPS);
    }
}
__global__ void fb_scatter(const float* __restrict__ x, const int* __restrict__ src,
                           const int* __restrict__ dst, const float* __restrict__ norm,
                           float* __restrict__ out, int E) {
    long long tid = (long long)blockIdx.x * blockDim.x + threadIdx.x;
    int e = (int)(tid >> 6), d = (int)(tid & 63);
    if (e < E) {
        int s = src[e], t = dst[e];
        atomicAdd(&out[(size_t)t * D + d], norm[s] * norm[t] * x[(size_t)s * D + d]);
    }
}

// ---------------- launcher ----------------

extern "C" void kernel_launch(void* const* d_in, const int* in_sizes, int n_in,
                              void* d_out, int out_size, void* d_ws, size_t ws_size,
                              hipStream_t stream) {
    const float* x   = (const float*)d_in[0];
    const int*   src = (const int*)d_in[1];
    const int*   dst = (const int*)d_in[2];
    float* out = (float*)d_out;

    const int ND = in_sizes[0];
    const int E  = in_sizes[1];
    const int n  = ND / D;
    const int NB = (n + BKT - 1) / BKT;
    constexpr int B = 256;
    const int NB64 = (NB + 63) & ~63;

    int capb = 0;
    for (int c : {4096, 3584}) {               // divisible by 16
        size_t srecB = ((size_t)NB * c + 15) & ~15ull;
        size_t need = (size_t)NB * c * 4                // rec (packed u32)
                    + srecB                             // srec (u8)
                    + (size_t)ND * 2                    // yh
                    + (size_t)n * 4                     // norm
                    + (size_t)(2 * NB64 + 128) * 4      // curD, curS, ovf_cnt, sovf_cnt
                    + (size_t)3 * MAXOVF * 4;           // ovf + sovf
        if (need <= ws_size) { capb = c; break; }
    }

    if (NB <= NBMAX && capb > 0 && n < (1 << 24)) {
        unsigned int* rec   = (unsigned int*)d_ws;                        // NB*capb u32
        unsigned char* srec = (unsigned char*)(rec + (size_t)NB * capb);  // NB*capb u8
        size_t srecB        = ((size_t)NB * capb + 15) & ~15ull;
        unsigned int* yh    = (unsigned int*)(srec + srecB);              // ND/2 u32
        float* norm         = (float*)(yh + ND / 2);                      // n
        int* curD           = (int*)(norm + n);                           // NB64
        int* curS           = curD + NB64;                                // NB64
        int* ovf_cnt        = curS + NB64;                                // 64
        int* sovf_cnt       = ovf_cnt + 64;                               // 64
        int* ovf            = sovf_cnt + 64;                              // 2*MAXOVF
        int* sovf           = ovf + 2 * MAXOVF;                           // MAXOVF

        // curD + curS + ovf_cnt + sovf_cnt zeroed in one DMA memset
        hipMemsetAsync(curD, 0, (size_t)(2 * NB64 + 128) * 4, stream);
        partition_kernel<<<(E + EPB - 1) / EPB, PTHREADS, 0, stream>>>(src, dst, curD, curS,
                                                                       rec, srec, ovf_cnt, ovf,
                                                                       sovf_cnt, sovf, E, NB, capb);
        normyh_kernel<<<NB, B, 0, stream>>>(srec, curS, sovf_cnt, sovf,
                                            (const float2*)x, yh, norm, n, capb);
        sortgather_kernel<<<NB, GTHREADS, 0, stream>>>(rec, curD, norm, (const uint4*)yh,
                                                       (const float4*)x, (float4*)out, n, capb);
        cleanup_kernel<<<32, B, 0, stream>>>(x, norm, ovf_cnt, ovf, out);
    } else {
        int*   deg  = (int*)d_ws;
        float* norm = (float*)d_ws + n;
        hipMemsetAsync(deg, 0, (size_t)n * sizeof(int), stream);
        fb_hist<<<(E + B - 1) / B, B, 0, stream>>>(src, deg, E);
        fb_norm<<<(n + B - 1) / B, B, 0, stream>>>(deg, norm, n);
        fb_init_out<<<(ND / 4 + B - 1) / B, B, 0, stream>>>((const float4*)x, (float4*)out, ND / 4);
        long long total = (long long)E * D;
        fb_scatter<<<(int)((total + B - 1) / B), B, 0, stream>>>(x, src, dst, norm, out, E);
    }
}